// Round 6
// baseline (514.840 us; speedup 1.0000x reference)
//
#include <hip/hip_runtime.h>
#include <math.h>

#define HID 256
#define PTS 16                 // points per block
#define NSTR 5                 // value, g0, g1, g2, laplacian-sum T
#define ROWS (NSTR*PTS)        // 80
#define PITCH 272              // halves; 544B row stride; A-frag reads near bank floor

typedef __fp16  fp16x2 __attribute__((ext_vector_type(2)));
typedef _Float16 half8  __attribute__((ext_vector_type(8)));
typedef float   floatx4 __attribute__((ext_vector_type(4)));

constexpr double PI_D = 3.14159265358979323846;
constexpr float K2F = (float)((343.0/(2.0*PI_D*1000.0))*(343.0/(2.0*PI_D*1000.0)));

union H2U { fp16x2 h; unsigned int u; };
__device__ __forceinline__ unsigned int pk(float a, float b) {
  H2U t; t.h = __builtin_amdgcn_cvt_pkrtz(a, b); return t.u;
}

__device__ __forceinline__ float tanh_fast(float z) {
  // tanh(z) = 1 - 2/(exp2(z*2*log2e)+1); v_exp_f32 is 2^x
  float e = __builtin_amdgcn_exp2f(z * 2.8853900817779268f);
  return 1.0f - 2.0f * __builtin_amdgcn_rcpf(e + 1.0f);
}

// Pack W2,W3 (fp32 row-major [k][n]) into fp16 B-fragment order for
// v_mfma_f32_16x16x32_f16, with a COLUMN PERMUTATION so one lane's 4 tiles
// hold 4 CONSECUTIVE logical columns: tile nt=w*4+c, slot m -> n = w*64+m*4+c
// Block 64: precompute wsq[n] = sum_i W1[i][n]^2 (used by L1 stream 4).
__global__ void pack_kernel(const float* __restrict__ W2, const float* __restrict__ W3,
                            const float* __restrict__ W1,
                            _Float16* __restrict__ out, float* __restrict__ wsq) {
  if (blockIdx.x == 64) {
    int n = threadIdx.x;   // 0..255
    float w0 = W1[0*HID + n], w1 = W1[1*HID + n], w2 = W1[2*HID + n];
    wsq[n] = fmaf(w0, w0, fmaf(w1, w1, w2*w2));
    return;
  }
  int t = blockIdx.x * blockDim.x + threadIdx.x;   // 0..16383
  int l    = t >> 13;
  int rem  = t & 8191;
  int kc   = rem >> 10;
  int nt   = (rem >> 6) & 15;
  int lane = rem & 63;
  const float* W = l ? W3 : W2;
  int k0 = kc*32 + ((lane >> 4) << 3);
  int n  = (nt >> 2)*64 + (lane & 15)*4 + (nt & 3);   // permuted column
  _Float16* o = out + (size_t)t * 8;
  #pragma unroll
  for (int j = 0; j < 8; ++j)
    o[j] = (_Float16)W[(size_t)(k0 + j)*HID + n];
}

__global__ __launch_bounds__(256, 3) void helm_kernel(
    const float* __restrict__ inputs,
    const float* __restrict__ W1, const float* __restrict__ b1,
    const float* __restrict__ b2, const float* __restrict__ b3,
    const float* __restrict__ W4, const float* __restrict__ b4,
    const _Float16* __restrict__ Wpack,   // [2][65536] fp16, B-frag packed+permuted
    const float* __restrict__ wsqv,       // [256] per-column sum of W1 squares
    float* __restrict__ part)             // [gridDim.x] block partial sums
{
  __shared__ __align__(16) _Float16 X[ROWS][PITCH];

  const int tid  = threadIdx.x;
  const int lane = tid & 63;
  const int wave = tid >> 6;
  const int m    = lane & 15;
  const int q    = lane >> 4;

  const int pbase = blockIdx.x * PTS;

  // ---------------- Layer 1: 3 -> 256 (VALU), packed staging ----------------
  {
    const int p  = tid >> 4;          // one point per 16 threads
    const int c0 = (tid & 15) * 16;   // 16 columns per thread
    const float x0 = inputs[(size_t)(pbase + p)*3 + 0];
    const float x1 = inputs[(size_t)(pbase + p)*3 + 1];
    const float x2 = inputs[(size_t)(pbase + p)*3 + 2];
    #pragma unroll
    for (int ch = 0; ch < 2; ++ch) {
      float v[NSTR][8];
      #pragma unroll
      for (int jj = 0; jj < 2; ++jj) {
        const int n = c0 + ch*8 + jj*4;
        floatx4 w0 = *(const floatx4*)&W1[0*HID + n];
        floatx4 w1 = *(const floatx4*)&W1[1*HID + n];
        floatx4 w2 = *(const floatx4*)&W1[2*HID + n];
        floatx4 bn = *(const floatx4*)&b1[n];
        floatx4 ws = *(const floatx4*)&wsqv[n];
        #pragma unroll
        for (int e = 0; e < 4; ++e) {
          float z  = fmaf(x2, w2[e], fmaf(x1, w1[e], fmaf(x0, w0[e], bn[e])));
          float a  = tanh_fast(z);
          float dd = 1.0f - a*a;
          v[0][jj*4+e] = a;
          v[1][jj*4+e] = dd*w0[e];
          v[2][jj*4+e] = dd*w1[e];
          v[3][jj*4+e] = dd*w2[e];
          v[4][jj*4+e] = -2.0f*a*dd*ws[e];
        }
      }
      #pragma unroll
      for (int s = 0; s < NSTR; ++s) {
        uint4 u;
        u.x = pk(v[s][0], v[s][1]); u.y = pk(v[s][2], v[s][3]);
        u.z = pk(v[s][4], v[s][5]); u.w = pk(v[s][6], v[s][7]);
        *(uint4*)&X[s*PTS + p][c0 + ch*8] = u;   // b128, 16B aligned
      }
    }
  }
  __syncthreads();

  const int colbase = wave*64 + m*4;   // this lane's 4 consecutive logical cols
  const _Float16* wb2 = Wpack + (((size_t)(wave*4)*64 + lane) << 3);
  const _Float16* wb3 = wb2 + 65536;

  // ---- half K-loop: X (5 streams) @ coltiles {off,off+1} -> acc[5][2] ----
  // Round-0 schedule preserved: all 5 afrags loaded back-to-back (latency
  // amortized over 5 outstanding LDS reads), then the 10-MFMA burst.
  auto kloop_half = [&](const _Float16* __restrict__ wb, int off,
                        floatx4 (&acc)[NSTR][2]) {
    #pragma unroll
    for (int s = 0; s < NSTR; ++s)
      #pragma unroll
      for (int c = 0; c < 2; ++c)
        acc[s][c] = (floatx4){0.0f, 0.0f, 0.0f, 0.0f};
    #pragma unroll
    for (int kc = 0; kc < 8; ++kc) {
      half8 bfrag[2];
      #pragma unroll
      for (int c = 0; c < 2; ++c)
        bfrag[c] = *(const half8*)(wb + (size_t)kc*8192 + (off + c)*512);
      half8 afrag[NSTR];
      #pragma unroll
      for (int s = 0; s < NSTR; ++s)
        afrag[s] = *(const half8*)(&X[s*PTS + m][kc*32 + q*8]);
      #pragma unroll
      for (int s = 0; s < NSTR; ++s)
        #pragma unroll
        for (int c = 0; c < 2; ++c)
          acc[s][c] = __builtin_amdgcn_mfma_f32_16x16x32_f16(afrag[s], bfrag[c], acc[s][c], 0, 0, 0);
    }
  };

  // combine one (row r, col-pair {cl,cl+1}) from acc2 -> 5 packed uints
  auto combine_pair = [&](floatx4 (&acc2)[NSTR][2], float bv0, float bv1,
                          unsigned int (&o)[NSTR]) {
    float t0[NSTR], t1[NSTR];
    #pragma unroll
    for (int c2 = 0; c2 < 2; ++c2) {
      float z  = acc2[0][c2][0] + (c2 ? bv1 : bv0);   // [0] overwritten below
      (void)z;
      t0[0] = t0[0]; // placeholder, real body below
    }
    (void)t0; (void)t1; (void)o;
  };
  (void)combine_pair; // unused helper shell (kept out; explicit bodies below)

  floatx4 acc01[NSTR][2], acc23[NSTR][2];
  unsigned int bufA[4][5];

  // ================= Layer 2 =================
  // Phase A: MFMA for coltiles {0,1}
  kloop_half(wb2, 0, acc01);

  // Phase B: MFMA for coltiles {2,3} fused with combine of {0,1} (pure-reg,
  // results buffered; X writes deferred past the barrier). One combine unit
  // (row r = kc/2, both cols) every other kc -> VALU issues into the gaps
  // while the matrix pipe executes the 10-MFMA bursts.
  {
    const float bv0 = b2[colbase + 0];
    const float bv1 = b2[colbase + 1];
    #pragma unroll
    for (int s = 0; s < NSTR; ++s)
      #pragma unroll
      for (int c = 0; c < 2; ++c)
        acc23[s][c] = (floatx4){0.0f, 0.0f, 0.0f, 0.0f};
    #pragma unroll
    for (int kc = 0; kc < 8; ++kc) {
      half8 bfrag[2];
      #pragma unroll
      for (int c = 0; c < 2; ++c)
        bfrag[c] = *(const half8*)(wb2 + (size_t)kc*8192 + (2 + c)*512);
      half8 afrag[NSTR];
      #pragma unroll
      for (int s = 0; s < NSTR; ++s)
        afrag[s] = *(const half8*)(&X[s*PTS + m][kc*32 + q*8]);
      #pragma unroll
      for (int s = 0; s < NSTR; ++s)
        #pragma unroll
        for (int c = 0; c < 2; ++c)
          acc23[s][c] = __builtin_amdgcn_mfma_f32_16x16x32_f16(afrag[s], bfrag[c], acc23[s][c], 0, 0, 0);
      if ((kc & 1) == 0) {
        const int r = kc >> 1;
        float o0[NSTR], o1[NSTR];
        #pragma unroll
        for (int c2 = 0; c2 < 2; ++c2) {
          float z  = acc01[0][c2][r] + (c2 ? bv1 : bv0);
          float a  = tanh_fast(z);
          float dd = 1.0f - a*a;
          float z0 = acc01[1][c2][r], z1 = acc01[2][c2][r], z2 = acc01[3][c2][r];
          float zpp = acc01[4][c2][r];
          float s2 = fmaf(z0, z0, fmaf(z1, z1, z2*z2));
          float* o = c2 ? o1 : o0;
          o[0] = a;
          o[1] = dd*z0; o[2] = dd*z1; o[3] = dd*z2;
          o[4] = fmaf(dd, zpp, -2.0f*a*dd*s2);
        }
        #pragma unroll
        for (int s = 0; s < NSTR; ++s)
          bufA[r][s] = pk(o0[s], o1[s]);
      }
    }
  }
  __syncthreads();   // all A-reads of X done; X writable

  // Phase C: write buffered {0,1} results; combine + write {2,3}
  {
    const float bv2 = b2[colbase + 2];
    const float bv3v = b2[colbase + 3];
    #pragma unroll
    for (int r = 0; r < 4; ++r) {
      const int p = q*4 + r;          // D-layout: row = quad*4 + reg
      #pragma unroll
      for (int s = 0; s < NSTR; ++s)
        *(unsigned int*)&X[s*PTS + p][colbase] = bufA[r][s];
      float o0[NSTR], o1[NSTR];
      #pragma unroll
      for (int c2 = 0; c2 < 2; ++c2) {
        float z  = acc23[0][c2][r] + (c2 ? bv3v : bv2);
        float a  = tanh_fast(z);
        float dd = 1.0f - a*a;
        float z0 = acc23[1][c2][r], z1 = acc23[2][c2][r], z2 = acc23[3][c2][r];
        float zpp = acc23[4][c2][r];
        float s2 = fmaf(z0, z0, fmaf(z1, z1, z2*z2));
        float* o = c2 ? o1 : o0;
        o[0] = a;
        o[1] = dd*z0; o[2] = dd*z1; o[3] = dd*z2;
        o[4] = fmaf(dd, zpp, -2.0f*a*dd*s2);
      }
      #pragma unroll
      for (int s = 0; s < NSTR; ++s)
        *(unsigned int*)&X[s*PTS + p][colbase + 2] = pk(o0[s], o1[s]);
    }
  }
  __syncthreads();   // layer-3 input ready

  // ================= Layer 3 =================
  float su[4] = {0,0,0,0}, st[4] = {0,0,0,0};

  // Phase A: MFMA for coltiles {0,1}
  kloop_half(wb3, 0, acc01);

  // Phase B: MFMA for coltiles {2,3} fused with E3 of {0,1} (register-only).
  // One (r,c) unit per kc.
  {
    const float bva[2] = { b3[colbase + 0], b3[colbase + 1] };
    const float w4a[2] = { W4[colbase + 0], W4[colbase + 1] };
    #pragma unroll
    for (int s = 0; s < NSTR; ++s)
      #pragma unroll
      for (int c = 0; c < 2; ++c)
        acc23[s][c] = (floatx4){0.0f, 0.0f, 0.0f, 0.0f};
    #pragma unroll
    for (int kc = 0; kc < 8; ++kc) {
      half8 bfrag[2];
      #pragma unroll
      for (int c = 0; c < 2; ++c)
        bfrag[c] = *(const half8*)(wb3 + (size_t)kc*8192 + (2 + c)*512);
      half8 afrag[NSTR];
      #pragma unroll
      for (int s = 0; s < NSTR; ++s)
        afrag[s] = *(const half8*)(&X[s*PTS + m][kc*32 + q*8]);
      #pragma unroll
      for (int s = 0; s < NSTR; ++s)
        #pragma unroll
        for (int c = 0; c < 2; ++c)
          acc23[s][c] = __builtin_amdgcn_mfma_f32_16x16x32_f16(afrag[s], bfrag[c], acc23[s][c], 0, 0, 0);
      {
        const int r = kc >> 1, c2 = kc & 1;
        float z  = acc01[0][c2][r] + bva[c2];
        float a  = tanh_fast(z);
        float dd = 1.0f - a*a;
        float z0 = acc01[1][c2][r], z1 = acc01[2][c2][r], z2 = acc01[3][c2][r];
        float zpp = acc01[4][c2][r];
        float s2 = fmaf(z0, z0, fmaf(z1, z1, z2*z2));
        float T  = fmaf(dd, zpp, -2.0f*a*dd*s2);
        su[r] = fmaf(a, w4a[c2], su[r]);
        st[r] = fmaf(T, w4a[c2], st[r]);
      }
    }
  }

  // E3 for coltiles {2,3}
  {
    const float bvb[2] = { b3[colbase + 2], b3[colbase + 3] };
    const float w4b[2] = { W4[colbase + 2], W4[colbase + 3] };
    #pragma unroll
    for (int r = 0; r < 4; ++r)
      #pragma unroll
      for (int c2 = 0; c2 < 2; ++c2) {
        float z  = acc23[0][c2][r] + bvb[c2];
        float a  = tanh_fast(z);
        float dd = 1.0f - a*a;
        float z0 = acc23[1][c2][r], z1 = acc23[2][c2][r], z2 = acc23[3][c2][r];
        float zpp = acc23[4][c2][r];
        float s2 = fmaf(z0, z0, fmaf(z1, z1, z2*z2));
        float T  = fmaf(dd, zpp, -2.0f*a*dd*s2);
        su[r] = fmaf(a, w4b[c2], su[r]);
        st[r] = fmaf(T, w4b[c2], st[r]);
      }
  }

  // reduce the 16 m-lanes of each quad (lanes q*16..q*16+15 share points)
  #pragma unroll
  for (int off = 8; off >= 1; off >>= 1)
    #pragma unroll
    for (int r = 0; r < 4; ++r) {
      su[r] += __shfl_down(su[r], off);
      st[r] += __shfl_down(st[r], off);
    }
  __syncthreads();   // all waves done with X reads; X reusable as scratch
  {
    float* S = (float*)X;   // scratch: 128 floats
    if (m == 0) {
      #pragma unroll
      for (int r = 0; r < 4; ++r) {
        S[(q*4 + r)*8 + wave]     = su[r];
        S[(q*4 + r)*8 + 4 + wave] = st[r];
      }
    }
  }
  __syncthreads();

  if (wave == 0) {
    const float* S = (const float*)X;
    int pidx = lane >> 2, w = lane & 3;
    float suc = S[pidx*8 + w];
    float stc = S[pidx*8 + 4 + w];
    suc += __shfl_down(suc, 1); suc += __shfl_down(suc, 2);
    stc += __shfl_down(stc, 1); stc += __shfl_down(stc, 2);
    float sq = 0.0f;
    if ((lane & 3) == 0) {
      float u   = suc + b4[0];
      float res = fmaf(K2F, u, stc);
      sq = res * res;
    }
    sq += __shfl_down(sq, 4); sq += __shfl_down(sq, 8);
    sq += __shfl_down(sq, 16); sq += __shfl_down(sq, 32);
    if (lane == 0) part[blockIdx.x] = sq;
  }
}

// 16384 block partials -> single mean; one block, no atomics.
__global__ void reduce_kernel(const float* __restrict__ part, float* __restrict__ out,
                              int nblk, float scale) {
  float s = 0.0f;
  for (int i = threadIdx.x; i < (nblk >> 2); i += 256) {
    floatx4 v = *(const floatx4*)&part[i << 2];
    s += (v[0] + v[1]) + (v[2] + v[3]);
  }
  #pragma unroll
  for (int off = 32; off; off >>= 1) s += __shfl_down(s, off);
  __shared__ float sm[4];
  if ((threadIdx.x & 63) == 0) sm[threadIdx.x >> 6] = s;
  __syncthreads();
  if (threadIdx.x == 0) out[0] = ((sm[0] + sm[1]) + (sm[2] + sm[3])) * scale;
}

extern "C" void kernel_launch(void* const* d_in, const int* in_sizes, int n_in,
                              void* d_out, int out_size, void* d_ws, size_t ws_size,
                              hipStream_t stream) {
  const float* inputs = (const float*)d_in[0];
  const float* W1 = (const float*)d_in[1];
  const float* b1 = (const float*)d_in[2];
  const float* W2 = (const float*)d_in[3];
  const float* b2 = (const float*)d_in[4];
  const float* W3 = (const float*)d_in[5];
  const float* b3 = (const float*)d_in[6];
  const float* W4 = (const float*)d_in[7];
  const float* b4 = (const float*)d_in[8];
  float* out = (float*)d_out;

  _Float16* wp   = (_Float16*)d_ws;                        // 256 KiB packed weights
  float*    part = (float*)((char*)d_ws + 2*65536*2);      // + 64 KiB block partials
  float*    wsq  = (float*)((char*)d_ws + 2*65536*2 + 65536);  // + 1 KiB col sums

  int N    = in_sizes[0] / 3;   // 262144
  int nblk = N / PTS;           // 16384

  pack_kernel<<<65, 256, 0, stream>>>(W2, W3, W1, wp, wsq);
  helm_kernel<<<nblk, 256, 0, stream>>>(inputs, W1, b1, b2, b3, W4, b4, wp, wsq, part);
  reduce_kernel<<<1, 256, 0, stream>>>(part, out, nblk, 1.0f / (float)N);
}

// Round 7
// 444.483 us; speedup vs baseline: 1.1583x; 1.1583x over previous
//
#include <hip/hip_runtime.h>
#include <math.h>

#define HID 256
#define PTS 16                 // points per block
#define NSTR 5                 // value, g0, g1, g2, laplacian-sum T
#define ROWS (NSTR*PTS)        // 80
#define PITCH 272              // halves; 544B row stride; A-frag reads near bank floor

typedef __fp16  fp16x2 __attribute__((ext_vector_type(2)));
typedef _Float16 half8  __attribute__((ext_vector_type(8)));
typedef float   floatx4 __attribute__((ext_vector_type(4)));

constexpr double PI_D = 3.14159265358979323846;
constexpr float K2F = (float)((343.0/(2.0*PI_D*1000.0))*(343.0/(2.0*PI_D*1000.0)));

union H2U { fp16x2 h; unsigned int u; };
__device__ __forceinline__ unsigned int pk(float a, float b) {
  H2U t; t.h = __builtin_amdgcn_cvt_pkrtz(a, b); return t.u;
}

__device__ __forceinline__ float tanh_fast(float z) {
  // tanh(z) = 1 - 2/(exp2(z*2*log2e)+1); v_exp_f32 is 2^x
  float e = __builtin_amdgcn_exp2f(z * 2.8853900817779268f);
  return 1.0f - 2.0f * __builtin_amdgcn_rcpf(e + 1.0f);
}

// Pack W2,W3 (fp32 row-major [k][n]) into fp16 B-fragment order for
// v_mfma_f32_16x16x32_f16, with a COLUMN PERMUTATION so one lane's 4 tiles
// hold 4 CONSECUTIVE logical columns: tile nt=w*4+c, slot m -> n = w*64+m*4+c
// Block 64: precompute wsq[n] = sum_i W1[i][n]^2 (used by L1 stream 4).
__global__ void pack_kernel(const float* __restrict__ W2, const float* __restrict__ W3,
                            const float* __restrict__ W1,
                            _Float16* __restrict__ out, float* __restrict__ wsq) {
  if (blockIdx.x == 64) {
    int n = threadIdx.x;   // 0..255
    float w0 = W1[0*HID + n], w1 = W1[1*HID + n], w2 = W1[2*HID + n];
    wsq[n] = fmaf(w0, w0, fmaf(w1, w1, w2*w2));
    return;
  }
  int t = blockIdx.x * blockDim.x + threadIdx.x;   // 0..16383
  int l    = t >> 13;
  int rem  = t & 8191;
  int kc   = rem >> 10;
  int nt   = (rem >> 6) & 15;
  int lane = rem & 63;
  const float* W = l ? W3 : W2;
  int k0 = kc*32 + ((lane >> 4) << 3);
  int n  = (nt >> 2)*64 + (lane & 15)*4 + (nt & 3);   // permuted column
  _Float16* o = out + (size_t)t * 8;
  #pragma unroll
  for (int j = 0; j < 8; ++j)
    o[j] = (_Float16)W[(size_t)(k0 + j)*HID + n];
}

// Occupancy 2 waves/SIMD (2 blocks/CU): 256-reg unified budget so the fused
// phases (acc01 40 + acc23 40 + bufA 20 + frags/temps) fit WITHOUT spilling.
// Round-6's identical code at (256,3) spilled ~18KB/block (WRITE_SIZE 300MB).
__global__ __launch_bounds__(256, 2) void helm_kernel(
    const float* __restrict__ inputs,
    const float* __restrict__ W1, const float* __restrict__ b1,
    const float* __restrict__ b2, const float* __restrict__ b3,
    const float* __restrict__ W4, const float* __restrict__ b4,
    const _Float16* __restrict__ Wpack,   // [2][65536] fp16, B-frag packed+permuted
    const float* __restrict__ wsqv,       // [256] per-column sum of W1 squares
    float* __restrict__ part)             // [gridDim.x] block partial sums
{
  __shared__ __align__(16) _Float16 X[ROWS][PITCH];

  const int tid  = threadIdx.x;
  const int lane = tid & 63;
  const int wave = tid >> 6;
  const int m    = lane & 15;
  const int q    = lane >> 4;

  const int pbase = blockIdx.x * PTS;

  // ---------------- Layer 1: 3 -> 256 (VALU), packed staging ----------------
  {
    const int p  = tid >> 4;          // one point per 16 threads
    const int c0 = (tid & 15) * 16;   // 16 columns per thread
    const float x0 = inputs[(size_t)(pbase + p)*3 + 0];
    const float x1 = inputs[(size_t)(pbase + p)*3 + 1];
    const float x2 = inputs[(size_t)(pbase + p)*3 + 2];
    #pragma unroll
    for (int ch = 0; ch < 2; ++ch) {
      float v[NSTR][8];
      #pragma unroll
      for (int jj = 0; jj < 2; ++jj) {
        const int n = c0 + ch*8 + jj*4;
        floatx4 w0 = *(const floatx4*)&W1[0*HID + n];
        floatx4 w1 = *(const floatx4*)&W1[1*HID + n];
        floatx4 w2 = *(const floatx4*)&W1[2*HID + n];
        floatx4 bn = *(const floatx4*)&b1[n];
        floatx4 ws = *(const floatx4*)&wsqv[n];
        #pragma unroll
        for (int e = 0; e < 4; ++e) {
          float z  = fmaf(x2, w2[e], fmaf(x1, w1[e], fmaf(x0, w0[e], bn[e])));
          float a  = tanh_fast(z);
          float dd = 1.0f - a*a;
          v[0][jj*4+e] = a;
          v[1][jj*4+e] = dd*w0[e];
          v[2][jj*4+e] = dd*w1[e];
          v[3][jj*4+e] = dd*w2[e];
          v[4][jj*4+e] = -2.0f*a*dd*ws[e];
        }
      }
      #pragma unroll
      for (int s = 0; s < NSTR; ++s) {
        uint4 u;
        u.x = pk(v[s][0], v[s][1]); u.y = pk(v[s][2], v[s][3]);
        u.z = pk(v[s][4], v[s][5]); u.w = pk(v[s][6], v[s][7]);
        *(uint4*)&X[s*PTS + p][c0 + ch*8] = u;   // b128, 16B aligned
      }
    }
  }
  __syncthreads();

  const int colbase = wave*64 + m*4;   // this lane's 4 consecutive logical cols
  const _Float16* wb2 = Wpack + (((size_t)(wave*4)*64 + lane) << 3);
  const _Float16* wb3 = wb2 + 65536;

  // ---- half K-loop: X (5 streams) @ coltiles {off,off+1} -> acc[5][2] ----
  auto kloop_half = [&](const _Float16* __restrict__ wb, int off,
                        floatx4 (&acc)[NSTR][2]) {
    #pragma unroll
    for (int s = 0; s < NSTR; ++s)
      #pragma unroll
      for (int c = 0; c < 2; ++c)
        acc[s][c] = (floatx4){0.0f, 0.0f, 0.0f, 0.0f};
    #pragma unroll
    for (int kc = 0; kc < 8; ++kc) {
      half8 bfrag[2];
      #pragma unroll
      for (int c = 0; c < 2; ++c)
        bfrag[c] = *(const half8*)(wb + (size_t)kc*8192 + (off + c)*512);
      half8 afrag[NSTR];
      #pragma unroll
      for (int s = 0; s < NSTR; ++s)
        afrag[s] = *(const half8*)(&X[s*PTS + m][kc*32 + q*8]);
      #pragma unroll
      for (int s = 0; s < NSTR; ++s)
        #pragma unroll
        for (int c = 0; c < 2; ++c)
          acc[s][c] = __builtin_amdgcn_mfma_f32_16x16x32_f16(afrag[s], bfrag[c], acc[s][c], 0, 0, 0);
    }
  };

  floatx4 acc01[NSTR][2], acc23[NSTR][2];
  unsigned int bufA[4][5];

  // ================= Layer 2 =================
  // Phase A: MFMA for coltiles {0,1}
  kloop_half(wb2, 0, acc01);

  // Phase B: MFMA for coltiles {2,3} fused with combine of {0,1} (pure-reg,
  // results buffered; X writes deferred past the barrier). One combine unit
  // (row r = kc/2, both cols) every other kc -> VALU issues into the gaps
  // while the matrix pipe executes the 10-MFMA bursts.
  {
    const float bv0 = b2[colbase + 0];
    const float bv1 = b2[colbase + 1];
    #pragma unroll
    for (int s = 0; s < NSTR; ++s)
      #pragma unroll
      for (int c = 0; c < 2; ++c)
        acc23[s][c] = (floatx4){0.0f, 0.0f, 0.0f, 0.0f};
    #pragma unroll
    for (int kc = 0; kc < 8; ++kc) {
      half8 bfrag[2];
      #pragma unroll
      for (int c = 0; c < 2; ++c)
        bfrag[c] = *(const half8*)(wb2 + (size_t)kc*8192 + (2 + c)*512);
      half8 afrag[NSTR];
      #pragma unroll
      for (int s = 0; s < NSTR; ++s)
        afrag[s] = *(const half8*)(&X[s*PTS + m][kc*32 + q*8]);
      #pragma unroll
      for (int s = 0; s < NSTR; ++s)
        #pragma unroll
        for (int c = 0; c < 2; ++c)
          acc23[s][c] = __builtin_amdgcn_mfma_f32_16x16x32_f16(afrag[s], bfrag[c], acc23[s][c], 0, 0, 0);
      if ((kc & 1) == 0) {
        const int r = kc >> 1;
        float o0[NSTR], o1[NSTR];
        #pragma unroll
        for (int c2 = 0; c2 < 2; ++c2) {
          float z  = acc01[0][c2][r] + (c2 ? bv1 : bv0);
          float a  = tanh_fast(z);
          float dd = 1.0f - a*a;
          float z0 = acc01[1][c2][r], z1 = acc01[2][c2][r], z2 = acc01[3][c2][r];
          float zpp = acc01[4][c2][r];
          float s2 = fmaf(z0, z0, fmaf(z1, z1, z2*z2));
          float* o = c2 ? o1 : o0;
          o[0] = a;
          o[1] = dd*z0; o[2] = dd*z1; o[3] = dd*z2;
          o[4] = fmaf(dd, zpp, -2.0f*a*dd*s2);
        }
        #pragma unroll
        for (int s = 0; s < NSTR; ++s)
          bufA[r][s] = pk(o0[s], o1[s]);
      }
    }
  }
  __syncthreads();   // all A-reads of X done; X writable

  // Phase C: write buffered {0,1} results; combine + write {2,3}
  {
    const float bv2 = b2[colbase + 2];
    const float bv3v = b2[colbase + 3];
    #pragma unroll
    for (int r = 0; r < 4; ++r) {
      const int p = q*4 + r;          // D-layout: row = quad*4 + reg
      #pragma unroll
      for (int s = 0; s < NSTR; ++s)
        *(unsigned int*)&X[s*PTS + p][colbase] = bufA[r][s];
      float o0[NSTR], o1[NSTR];
      #pragma unroll
      for (int c2 = 0; c2 < 2; ++c2) {
        float z  = acc23[0][c2][r] + (c2 ? bv3v : bv2);
        float a  = tanh_fast(z);
        float dd = 1.0f - a*a;
        float z0 = acc23[1][c2][r], z1 = acc23[2][c2][r], z2 = acc23[3][c2][r];
        float zpp = acc23[4][c2][r];
        float s2 = fmaf(z0, z0, fmaf(z1, z1, z2*z2));
        float* o = c2 ? o1 : o0;
        o[0] = a;
        o[1] = dd*z0; o[2] = dd*z1; o[3] = dd*z2;
        o[4] = fmaf(dd, zpp, -2.0f*a*dd*s2);
      }
      #pragma unroll
      for (int s = 0; s < NSTR; ++s)
        *(unsigned int*)&X[s*PTS + p][colbase + 2] = pk(o0[s], o1[s]);
    }
  }
  __syncthreads();   // layer-3 input ready

  // ================= Layer 3 =================
  float su[4] = {0,0,0,0}, st[4] = {0,0,0,0};

  // Phase A: MFMA for coltiles {0,1}
  kloop_half(wb3, 0, acc01);

  // Phase B: MFMA for coltiles {2,3} fused with E3 of {0,1} (register-only).
  // One (r,c) unit per kc.
  {
    const float bva[2] = { b3[colbase + 0], b3[colbase + 1] };
    const float w4a[2] = { W4[colbase + 0], W4[colbase + 1] };
    #pragma unroll
    for (int s = 0; s < NSTR; ++s)
      #pragma unroll
      for (int c = 0; c < 2; ++c)
        acc23[s][c] = (floatx4){0.0f, 0.0f, 0.0f, 0.0f};
    #pragma unroll
    for (int kc = 0; kc < 8; ++kc) {
      half8 bfrag[2];
      #pragma unroll
      for (int c = 0; c < 2; ++c)
        bfrag[c] = *(const half8*)(wb3 + (size_t)kc*8192 + (2 + c)*512);
      half8 afrag[NSTR];
      #pragma unroll
      for (int s = 0; s < NSTR; ++s)
        afrag[s] = *(const half8*)(&X[s*PTS + m][kc*32 + q*8]);
      #pragma unroll
      for (int s = 0; s < NSTR; ++s)
        #pragma unroll
        for (int c = 0; c < 2; ++c)
          acc23[s][c] = __builtin_amdgcn_mfma_f32_16x16x32_f16(afrag[s], bfrag[c], acc23[s][c], 0, 0, 0);
      {
        const int r = kc >> 1, c2 = kc & 1;
        float z  = acc01[0][c2][r] + bva[c2];
        float a  = tanh_fast(z);
        float dd = 1.0f - a*a;
        float z0 = acc01[1][c2][r], z1 = acc01[2][c2][r], z2 = acc01[3][c2][r];
        float zpp = acc01[4][c2][r];
        float s2 = fmaf(z0, z0, fmaf(z1, z1, z2*z2));
        float T  = fmaf(dd, zpp, -2.0f*a*dd*s2);
        su[r] = fmaf(a, w4a[c2], su[r]);
        st[r] = fmaf(T, w4a[c2], st[r]);
      }
    }
  }

  // E3 for coltiles {2,3}
  {
    const float bvb[2] = { b3[colbase + 2], b3[colbase + 3] };
    const float w4b[2] = { W4[colbase + 2], W4[colbase + 3] };
    #pragma unroll
    for (int r = 0; r < 4; ++r)
      #pragma unroll
      for (int c2 = 0; c2 < 2; ++c2) {
        float z  = acc23[0][c2][r] + bvb[c2];
        float a  = tanh_fast(z);
        float dd = 1.0f - a*a;
        float z0 = acc23[1][c2][r], z1 = acc23[2][c2][r], z2 = acc23[3][c2][r];
        float zpp = acc23[4][c2][r];
        float s2 = fmaf(z0, z0, fmaf(z1, z1, z2*z2));
        float T  = fmaf(dd, zpp, -2.0f*a*dd*s2);
        su[r] = fmaf(a, w4b[c2], su[r]);
        st[r] = fmaf(T, w4b[c2], st[r]);
      }
  }

  // reduce the 16 m-lanes of each quad (lanes q*16..q*16+15 share points)
  #pragma unroll
  for (int off = 8; off >= 1; off >>= 1)
    #pragma unroll
    for (int r = 0; r < 4; ++r) {
      su[r] += __shfl_down(su[r], off);
      st[r] += __shfl_down(st[r], off);
    }
  __syncthreads();   // all waves done with X reads; X reusable as scratch
  {
    float* S = (float*)X;   // scratch: 128 floats
    if (m == 0) {
      #pragma unroll
      for (int r = 0; r < 4; ++r) {
        S[(q*4 + r)*8 + wave]     = su[r];
        S[(q*4 + r)*8 + 4 + wave] = st[r];
      }
    }
  }
  __syncthreads();

  if (wave == 0) {
    const float* S = (const float*)X;
    int pidx = lane >> 2, w = lane & 3;
    float suc = S[pidx*8 + w];
    float stc = S[pidx*8 + 4 + w];
    suc += __shfl_down(suc, 1); suc += __shfl_down(suc, 2);
    stc += __shfl_down(stc, 1); stc += __shfl_down(stc, 2);
    float sq = 0.0f;
    if ((lane & 3) == 0) {
      float u   = suc + b4[0];
      float res = fmaf(K2F, u, stc);
      sq = res * res;
    }
    sq += __shfl_down(sq, 4); sq += __shfl_down(sq, 8);
    sq += __shfl_down(sq, 16); sq += __shfl_down(sq, 32);
    if (lane == 0) part[blockIdx.x] = sq;
  }
}

// 16384 block partials -> single mean; one block, no atomics.
__global__ void reduce_kernel(const float* __restrict__ part, float* __restrict__ out,
                              int nblk, float scale) {
  float s = 0.0f;
  for (int i = threadIdx.x; i < (nblk >> 2); i += 256) {
    floatx4 v = *(const floatx4*)&part[i << 2];
    s += (v[0] + v[1]) + (v[2] + v[3]);
  }
  #pragma unroll
  for (int off = 32; off; off >>= 1) s += __shfl_down(s, off);
  __shared__ float sm[4];
  if ((threadIdx.x & 63) == 0) sm[threadIdx.x >> 6] = s;
  __syncthreads();
  if (threadIdx.x == 0) out[0] = ((sm[0] + sm[1]) + (sm[2] + sm[3])) * scale;
}

extern "C" void kernel_launch(void* const* d_in, const int* in_sizes, int n_in,
                              void* d_out, int out_size, void* d_ws, size_t ws_size,
                              hipStream_t stream) {
  const float* inputs = (const float*)d_in[0];
  const float* W1 = (const float*)d_in[1];
  const float* b1 = (const float*)d_in[2];
  const float* W2 = (const float*)d_in[3];
  const float* b2 = (const float*)d_in[4];
  const float* W3 = (const float*)d_in[5];
  const float* b3 = (const float*)d_in[6];
  const float* W4 = (const float*)d_in[7];
  const float* b4 = (const float*)d_in[8];
  float* out = (float*)d_out;

  _Float16* wp   = (_Float16*)d_ws;                        // 256 KiB packed weights
  float*    part = (float*)((char*)d_ws + 2*65536*2);      // + 64 KiB block partials
  float*    wsq  = (float*)((char*)d_ws + 2*65536*2 + 65536);  // + 1 KiB col sums

  int N    = in_sizes[0] / 3;   // 262144
  int nblk = N / PTS;           // 16384

  pack_kernel<<<65, 256, 0, stream>>>(W2, W3, W1, wp, wsq);
  helm_kernel<<<nblk, 256, 0, stream>>>(inputs, W1, b1, b2, b3, W4, b4, wp, wsq, part);
  reduce_kernel<<<1, 256, 0, stream>>>(part, out, nblk, 1.0f / (float)N);
}

// Round 8
// 419.011 us; speedup vs baseline: 1.2287x; 1.0608x over previous
//
#include <hip/hip_runtime.h>
#include <math.h>

#define HID 256
#define PTS 16                 // points per block
#define NSTR 5                 // value, g0, g1, g2, laplacian-sum T
#define ROWS (NSTR*PTS)        // 80
#define PITCH 272              // halves; 544B row stride; A-frag reads near bank floor

typedef __fp16  fp16x2 __attribute__((ext_vector_type(2)));
typedef _Float16 half8  __attribute__((ext_vector_type(8)));
typedef float   floatx4 __attribute__((ext_vector_type(4)));

constexpr double PI_D = 3.14159265358979323846;
constexpr float K2F = (float)((343.0/(2.0*PI_D*1000.0))*(343.0/(2.0*PI_D*1000.0)));

union H2U { fp16x2 h; unsigned int u; };
__device__ __forceinline__ unsigned int pk(float a, float b) {
  H2U t; t.h = __builtin_amdgcn_cvt_pkrtz(a, b); return t.u;
}

__device__ __forceinline__ float tanh_fast(float z) {
  // tanh(z) = 1 - 2/(exp2(z*2*log2e)+1); v_exp_f32 is 2^x
  float e = __builtin_amdgcn_exp2f(z * 2.8853900817779268f);
  return 1.0f - 2.0f * __builtin_amdgcn_rcpf(e + 1.0f);
}

// Pack W2,W3 (fp32 row-major [k][n]) into fp16 B-fragment order for
// v_mfma_f32_16x16x32_f16, with a COLUMN PERMUTATION so one lane's 4 tiles
// hold 4 CONSECUTIVE logical columns: tile nt=w*4+c, slot m -> n = w*64+m*4+c
// Block 64: precompute wsq[n] = sum_i W1[i][n]^2 (used by L1 stream 4).
__global__ void pack_kernel(const float* __restrict__ W2, const float* __restrict__ W3,
                            const float* __restrict__ W1,
                            _Float16* __restrict__ out, float* __restrict__ wsq) {
  if (blockIdx.x == 64) {
    int n = threadIdx.x;   // 0..255
    float w0 = W1[0*HID + n], w1 = W1[1*HID + n], w2 = W1[2*HID + n];
    wsq[n] = fmaf(w0, w0, fmaf(w1, w1, w2*w2));
    return;
  }
  int t = blockIdx.x * blockDim.x + threadIdx.x;   // 0..16383
  int l    = t >> 13;
  int rem  = t & 8191;
  int kc   = rem >> 10;
  int nt   = (rem >> 6) & 15;
  int lane = rem & 63;
  const float* W = l ? W3 : W2;
  int k0 = kc*32 + ((lane >> 4) << 3);
  int n  = (nt >> 2)*64 + (lane & 15)*4 + (nt & 3);   // permuted column
  _Float16* o = out + (size_t)t * 8;
  #pragma unroll
  for (int j = 0; j < 8; ++j)
    o[j] = (_Float16)W[(size_t)(k0 + j)*HID + n];
}

__global__ __launch_bounds__(256, 3) void helm_kernel(
    const float* __restrict__ inputs,
    const float* __restrict__ W1, const float* __restrict__ b1,
    const float* __restrict__ b2, const float* __restrict__ b3,
    const float* __restrict__ W4, const float* __restrict__ b4,
    const _Float16* __restrict__ Wpack,   // [2][65536] fp16, B-frag packed+permuted
    const float* __restrict__ wsqv,       // [256] per-column sum of W1 squares
    float* __restrict__ part)             // [gridDim.x] block partial sums
{
  __shared__ __align__(16) _Float16 X[ROWS][PITCH];

  const int tid  = threadIdx.x;
  const int lane = tid & 63;
  const int wave = tid >> 6;
  const int m    = lane & 15;
  const int q    = lane >> 4;

  // ---- first-generation phase stagger (no HW_ID, no atomics) ----
  // Initial dispatch round-robins blocks over 8 XCDs x 32 CUs, so the first
  // 3 blocks co-resident on a CU are {b, b+256, b+512}. Offset them by
  // ~1/3 and ~2/3 of a block's runtime so the MFMA and VALU phases of the
  // 3 resident blocks decorrelate (m114: MFMA-wave + VALU-wave on one CU
  // overlap fully). Later blocks inherit offsets from staggered completions.
  if (blockIdx.x < 768) {
    int ph = blockIdx.x >> 8;                      // 0,1,2
    if (ph > 0) __builtin_amdgcn_s_sleep(70);      // ~4.5k cycles
    if (ph > 1) __builtin_amdgcn_s_sleep(70);      // ~9k total for phase 2
  }

  const int pbase = blockIdx.x * PTS;

  // ---------------- Layer 1: 3 -> 256 (VALU), packed staging ----------------
  {
    const int p  = tid >> 4;          // one point per 16 threads
    const int c0 = (tid & 15) * 16;   // 16 columns per thread
    const float x0 = inputs[(size_t)(pbase + p)*3 + 0];
    const float x1 = inputs[(size_t)(pbase + p)*3 + 1];
    const float x2 = inputs[(size_t)(pbase + p)*3 + 2];
    #pragma unroll
    for (int ch = 0; ch < 2; ++ch) {
      float v[NSTR][8];
      #pragma unroll
      for (int jj = 0; jj < 2; ++jj) {
        const int n = c0 + ch*8 + jj*4;
        floatx4 w0 = *(const floatx4*)&W1[0*HID + n];
        floatx4 w1 = *(const floatx4*)&W1[1*HID + n];
        floatx4 w2 = *(const floatx4*)&W1[2*HID + n];
        floatx4 bn = *(const floatx4*)&b1[n];
        floatx4 ws = *(const floatx4*)&wsqv[n];
        #pragma unroll
        for (int e = 0; e < 4; ++e) {
          float z  = fmaf(x2, w2[e], fmaf(x1, w1[e], fmaf(x0, w0[e], bn[e])));
          float a  = tanh_fast(z);
          float dd = 1.0f - a*a;
          v[0][jj*4+e] = a;
          v[1][jj*4+e] = dd*w0[e];
          v[2][jj*4+e] = dd*w1[e];
          v[3][jj*4+e] = dd*w2[e];
          v[4][jj*4+e] = -2.0f*a*dd*ws[e];
        }
      }
      #pragma unroll
      for (int s = 0; s < NSTR; ++s) {
        uint4 u;
        u.x = pk(v[s][0], v[s][1]); u.y = pk(v[s][2], v[s][3]);
        u.z = pk(v[s][4], v[s][5]); u.w = pk(v[s][6], v[s][7]);
        *(uint4*)&X[s*PTS + p][c0 + ch*8] = u;   // b128, 16B aligned
      }
    }
  }
  __syncthreads();

  const int colbase = wave*64 + m*4;   // this lane's 4 consecutive logical cols

  // ---- shared K-loop: X (5 streams) @ Wpack-layer -> acc[5][4] ----
  // acc must be pre-initialized by caller (stream 0 carries the folded bias).
  auto kloop = [&](const _Float16* __restrict__ Wp, floatx4 (&acc)[NSTR][4]) {
    const _Float16* wb = Wp + (((size_t)(wave*4)*64 + lane) << 3);
    #pragma unroll
    for (int kc = 0; kc < 8; ++kc) {
      half8 bfrag[4];
      #pragma unroll
      for (int c = 0; c < 4; ++c)
        bfrag[c] = *(const half8*)(wb + (size_t)kc*8192 + c*512);
      half8 afrag[NSTR];
      #pragma unroll
      for (int s = 0; s < NSTR; ++s)
        afrag[s] = *(const half8*)(&X[s*PTS + m][kc*32 + q*8]);
      // MFMA burst at raised priority (T5): pays off when resident blocks
      // are phase-staggered; harmless in lockstep (m190).
      __builtin_amdgcn_s_setprio(1);
      #pragma unroll
      for (int s = 0; s < NSTR; ++s)
        #pragma unroll
        for (int c = 0; c < 4; ++c)
          acc[s][c] = __builtin_amdgcn_mfma_f32_16x16x32_f16(afrag[s], bfrag[c], acc[s][c], 0, 0, 0);
      __builtin_amdgcn_s_setprio(0);
    }
  };

  // ---------------- Layer 2: MFMA + combine (writes X) ----------------
  {
    floatx4 bv = *(const floatx4*)&b2[colbase];
    floatx4 acc[NSTR][4];
    #pragma unroll
    for (int c = 0; c < 4; ++c) {
      // bias folded into the accumulator: all 4 r-slots of a lane share col c
      acc[0][c] = (floatx4){bv[c], bv[c], bv[c], bv[c]};
      #pragma unroll
      for (int s = 1; s < NSTR; ++s)
        acc[s][c] = (floatx4){0.0f, 0.0f, 0.0f, 0.0f};
    }
    kloop(Wpack, acc);
    __syncthreads();   // all A-reads done; X writable

    #pragma unroll
    for (int r = 0; r < 4; ++r) {
      const int p = q*4 + r;          // D-layout: row = quad*4 + reg
      float va[4], vg0[4], vg1[4], vg2[4], vT[4];
      #pragma unroll
      for (int c = 0; c < 4; ++c) {
        float z  = acc[0][c][r];      // bias already in acc
        float a  = tanh_fast(z);
        float dd = 1.0f - a*a;
        float z0 = acc[1][c][r], z1 = acc[2][c][r], z2 = acc[3][c][r];
        float zpp = acc[4][c][r];
        float s2 = fmaf(z0, z0, fmaf(z1, z1, z2*z2));
        va[c]  = a;
        vg0[c] = dd*z0; vg1[c] = dd*z1; vg2[c] = dd*z2;
        vT[c]  = fmaf(dd, zpp, -2.0f*a*dd*s2);
      }
      uint2 u;
      u.x = pk(va[0],va[1]);   u.y = pk(va[2],va[3]);   *(uint2*)&X[0*PTS + p][colbase] = u;
      u.x = pk(vg0[0],vg0[1]); u.y = pk(vg0[2],vg0[3]); *(uint2*)&X[1*PTS + p][colbase] = u;
      u.x = pk(vg1[0],vg1[1]); u.y = pk(vg1[2],vg1[3]); *(uint2*)&X[2*PTS + p][colbase] = u;
      u.x = pk(vg2[0],vg2[1]); u.y = pk(vg2[2],vg2[3]); *(uint2*)&X[3*PTS + p][colbase] = u;
      u.x = pk(vT[0],vT[1]);   u.y = pk(vT[2],vT[3]);   *(uint2*)&X[4*PTS + p][colbase] = u;
    }
    __syncthreads();
  }

  // ------- Layer 3 MFMA + fused (combine ∘ layer-4 ∘ residual) -------
  {
    floatx4 bv = *(const floatx4*)&b3[colbase];
    floatx4 acc[NSTR][4];
    #pragma unroll
    for (int c = 0; c < 4; ++c) {
      acc[0][c] = (floatx4){bv[c], bv[c], bv[c], bv[c]};
      #pragma unroll
      for (int s = 1; s < NSTR; ++s)
        acc[s][c] = (floatx4){0.0f, 0.0f, 0.0f, 0.0f};
    }
    kloop(Wpack + 65536, acc);
    __syncthreads();   // all A-reads done; X reusable as scratch

    floatx4 w4 = *(const floatx4*)&W4[colbase];
    float su[4] = {0,0,0,0}, st[4] = {0,0,0,0};
    #pragma unroll
    for (int r = 0; r < 4; ++r)
      #pragma unroll
      for (int c = 0; c < 4; ++c) {
        float z  = acc[0][c][r];      // bias already in acc
        float a  = tanh_fast(z);
        float dd = 1.0f - a*a;
        float z0 = acc[1][c][r], z1 = acc[2][c][r], z2 = acc[3][c][r];
        float zpp = acc[4][c][r];
        float s2 = fmaf(z0, z0, fmaf(z1, z1, z2*z2));
        float T  = fmaf(dd, zpp, -2.0f*a*dd*s2);
        su[r] = fmaf(a, w4[c], su[r]);   // u-partial for point p=q*4+r
        st[r] = fmaf(T, w4[c], st[r]);   // laplacian-partial
      }

    // reduce the 16 m-lanes of each quad (lanes q*16..q*16+15 share points)
    #pragma unroll
    for (int off = 8; off >= 1; off >>= 1)
      #pragma unroll
      for (int r = 0; r < 4; ++r) {
        su[r] += __shfl_down(su[r], off);
        st[r] += __shfl_down(st[r], off);
      }
    float* S = (float*)X;   // scratch: 128 floats, reuse of X (post-barrier)
    if (m == 0) {
      #pragma unroll
      for (int r = 0; r < 4; ++r) {
        S[(q*4 + r)*8 + wave]     = su[r];
        S[(q*4 + r)*8 + 4 + wave] = st[r];
      }
    }
  }
  __syncthreads();

  if (wave == 0) {
    const float* S = (const float*)X;
    int pidx = lane >> 2, w = lane & 3;
    float suc = S[pidx*8 + w];
    float stc = S[pidx*8 + 4 + w];
    suc += __shfl_down(suc, 1); suc += __shfl_down(suc, 2);
    stc += __shfl_down(stc, 1); stc += __shfl_down(stc, 2);
    float sq = 0.0f;
    if ((lane & 3) == 0) {
      float u   = suc + b4[0];
      float res = fmaf(K2F, u, stc);
      sq = res * res;
    }
    sq += __shfl_down(sq, 4); sq += __shfl_down(sq, 8);
    sq += __shfl_down(sq, 16); sq += __shfl_down(sq, 32);
    if (lane == 0) part[blockIdx.x] = sq;
  }
}

// 16384 block partials -> single mean; one block, no atomics.
__global__ void reduce_kernel(const float* __restrict__ part, float* __restrict__ out,
                              int nblk, float scale) {
  float s = 0.0f;
  for (int i = threadIdx.x; i < (nblk >> 2); i += 256) {
    floatx4 v = *(const floatx4*)&part[i << 2];
    s += (v[0] + v[1]) + (v[2] + v[3]);
  }
  #pragma unroll
  for (int off = 32; off; off >>= 1) s += __shfl_down(s, off);
  __shared__ float sm[4];
  if ((threadIdx.x & 63) == 0) sm[threadIdx.x >> 6] = s;
  __syncthreads();
  if (threadIdx.x == 0) out[0] = ((sm[0] + sm[1]) + (sm[2] + sm[3])) * scale;
}

extern "C" void kernel_launch(void* const* d_in, const int* in_sizes, int n_in,
                              void* d_out, int out_size, void* d_ws, size_t ws_size,
                              hipStream_t stream) {
  const float* inputs = (const float*)d_in[0];
  const float* W1 = (const float*)d_in[1];
  const float* b1 = (const float*)d_in[2];
  const float* W2 = (const float*)d_in[3];
  const float* b2 = (const float*)d_in[4];
  const float* W3 = (const float*)d_in[5];
  const float* b3 = (const float*)d_in[6];
  const float* W4 = (const float*)d_in[7];
  const float* b4 = (const float*)d_in[8];
  float* out = (float*)d_out;

  _Float16* wp   = (_Float16*)d_ws;                        // 256 KiB packed weights
  float*    part = (float*)((char*)d_ws + 2*65536*2);      // + 64 KiB block partials
  float*    wsq  = (float*)((char*)d_ws + 2*65536*2 + 65536);  // + 1 KiB col sums

  int N    = in_sizes[0] / 3;   // 262144
  int nblk = N / PTS;           // 16384

  pack_kernel<<<65, 256, 0, stream>>>(W2, W3, W1, wp, wsq);
  helm_kernel<<<nblk, 256, 0, stream>>>(inputs, W1, b1, b2, b3, W4, b4, wp, wsq, part);
  reduce_kernel<<<1, 256, 0, stream>>>(part, out, nblk, 1.0f / (float)N);
}